// Round 10
// baseline (619.228 us; speedup 1.0000x reference)
//
#include <hip/hip_runtime.h>
#include <hip/hip_bf16.h>
#include <math.h>

#define DM   1024
#define DFF  4096
#define NHEAD 16
#define DKH  64
#define SEQ  2048
#define NBATCH 4
#define NTOK 8192          // NBATCH*SEQ

typedef __attribute__((ext_vector_type(8))) __bf16 bf16x8;
typedef __attribute__((ext_vector_type(8))) short short8;
typedef __attribute__((ext_vector_type(4))) float f32x4;
typedef __attribute__((ext_vector_type(16))) float f32x16;
typedef __attribute__((ext_vector_type(4))) unsigned int u32x4;
typedef __attribute__((ext_vector_type(4))) unsigned short ushort4v;

__device__ __forceinline__ unsigned short f2bf(float f) {
    unsigned u = __builtin_bit_cast(unsigned, f);
    u += 0x7fffu + ((u >> 16) & 1u);   // round-to-nearest-even
    return (unsigned short)(u >> 16);
}

__device__ __forceinline__ void gload_lds16(const void* g, void* l) {
    __builtin_amdgcn_global_load_lds(
        (const __attribute__((address_space(1))) unsigned int*)g,
        (__attribute__((address_space(3))) unsigned int*)l, 16, 0, 0);
}

#define LGKM0 do { asm volatile("s_waitcnt lgkmcnt(0)" ::: "memory"); \
                   __builtin_amdgcn_sched_barrier(0); } while (0)
#define SB0   __builtin_amdgcn_sched_barrier(0)

// ---------------- weight transpose + fp32->bf16 : dst[C][R] = src[R][C] ----------------
__global__ __launch_bounds__(256) void transpose_cvt(
        const float* __restrict__ src, unsigned short* __restrict__ dst, int R, int C) {
    __shared__ unsigned short tile[32][33];
    const int c0 = blockIdx.x * 32, r0 = blockIdx.y * 32;
    const int tx = threadIdx.x & 31, ty = threadIdx.x >> 5;   // ty 0..7
    #pragma unroll
    for (int j = 0; j < 32; j += 8)
        tile[ty + j][tx] = f2bf(src[(size_t)(r0 + ty + j) * C + (c0 + tx)]);
    __syncthreads();
    #pragma unroll
    for (int j = 0; j < 32; j += 8)
        dst[(size_t)(c0 + ty + j) * R + (r0 + tx)] = tile[tx][ty + j];
}

// ---------------- bias concat (bq|bk|bv) ----------------
__global__ __launch_bounds__(256) void concat_bias(
        const float* __restrict__ a, const float* __restrict__ b,
        const float* __restrict__ c, float* __restrict__ out) {
    int i = blockIdx.x * 256 + threadIdx.x;            // 0..3071
    out[i] = (i < 1024) ? a[i] : (i < 2048 ? b[i - 1024] : c[i - 2048]);
}

// ---------------- layernorm fp32 -> bf16 (one row per block) ----------------
__global__ __launch_bounds__(256) void ln_kernel(
        const float* __restrict__ x, const float* __restrict__ g,
        const float* __restrict__ b, unsigned short* __restrict__ out) {
    const int row = blockIdx.x, t = threadIdx.x;
    const float4 v = ((const float4*)(x + (size_t)row * DM))[t];
    float s1 = v.x + v.y + v.z + v.w;
    float s2 = v.x * v.x + v.y * v.y + v.z * v.z + v.w * v.w;
    #pragma unroll
    for (int off = 32; off > 0; off >>= 1) {
        s1 += __shfl_xor(s1, off, 64);
        s2 += __shfl_xor(s2, off, 64);
    }
    __shared__ float w1[4], w2[4];
    const int wid = t >> 6, lane = t & 63;
    if (lane == 0) { w1[wid] = s1; w2[wid] = s2; }
    __syncthreads();
    s1 = w1[0] + w1[1] + w1[2] + w1[3];
    s2 = w2[0] + w2[1] + w2[2] + w2[3];
    const float mu = s1 * (1.0f / DM);
    const float rs = rsqrtf(s2 * (1.0f / DM) - mu * mu + 1e-5f);
    const float4 gv = ((const float4*)g)[t];
    const float4 bv = ((const float4*)b)[t];
    ushort4v o;
    o[0] = f2bf((v.x - mu) * rs * gv.x + bv.x);
    o[1] = f2bf((v.y - mu) * rs * gv.y + bv.y);
    o[2] = f2bf((v.z - mu) * rs * gv.z + bv.z);
    o[3] = f2bf((v.w - mu) * rs * gv.w + bv.w);
    *(ushort4v*)(out + (size_t)row * DM + t * 4) = o;
}

// ======== m201-style 8-phase bf16 GEMM: gload_lds staging + counted vmcnt ========
// C[M,N] = A[M,K]*BT[N,K]^T + bias (+res). 512 thr = 8 waves (2M x 4N), BK=64.
// Per K-tile: 4 sub-phases, each {ds_read frags | stage chunks -> barrier ->
// lgkmcnt(0) -> setprio MFMA -> barrier}. One vmcnt(CHA+CHB) gate per tile (never 0).
// Stage placement respects region-read-completion: B free after P2, A after P3.
// EP: 0 bias->bf16 | 1 bias+res->f32 | 2 bias+GELU->bf16 | 3 bias+res->f32 | 4 QKV pack
template<int BM, int BN, int EP>
__global__ __launch_bounds__(512, 2) void gemmp(
        const unsigned short* __restrict__ A, const unsigned short* __restrict__ BT,
        const float* __restrict__ bias, const float* __restrict__ res,
        void* __restrict__ outp, int M, int N, int K) {
    constexpr int WM = BM / 2, WN = BN / 4;    // per-wave output span
    constexpr int MR = WM / 16, NR = WN / 16;  // fragment repeats
    constexpr int MH = MR / 2, NH = NR / 2;    // per-phase halves
    constexpr int CHA = BM / 64, CHB = BN / 64;// 8KB stage chunks per K-tile
    constexpr int VMN = CHA + CHB;             // counted vmcnt gate

    const int t = threadIdx.x;
    const int lane = t & 63, wid = t >> 6;
    const int wr = wid >> 2, wc = wid & 3;
    const int l15 = lane & 15, l7 = lane & 7, q4 = lane >> 4;
    const int m0 = blockIdx.y * BM, n0 = blockIdx.x * BN;
    const int NT = K >> 6;

    __shared__ alignas(16) short As[2 * BM * 64];
    __shared__ alignas(16) short Bs[2 * BN * 64];

    // staging: thread t covers row (t>>3), 16B chunk (t&7) of each 64-row chunk;
    // source pre-swizzled (chunk ^ row&7) so linear LDS dest holds swizzled layout
    const int srow = t >> 3;
    const int swz8 = (((t & 7) ^ (srow & 7)) << 3);
    const unsigned short* gAt = A  + (size_t)(m0 + srow) * K + swz8;
    const unsigned short* gBt = BT + (size_t)(n0 + srow) * K + swz8;

    bf16x8 fa[MH][2], fb[NR][2];
    f32x4 acc[MR][NR] = {};

    auto STG_A = [&](int tile, int ch) {
        gload_lds16(gAt + (size_t)ch * 64 * K + (size_t)tile * 64,
                    As + ((size_t)(tile & 1) * BM + ch * 64) * 64 + wid * 512);
    };
    auto STG_B = [&](int tile, int ch) {
        gload_lds16(gBt + (size_t)ch * 64 * K + (size_t)tile * 64,
                    Bs + ((size_t)(tile & 1) * BN + ch * 64) * 64 + wid * 512);
    };
    auto RD_FA = [&](int p, int mh) {
        const short* base = As + (size_t)p * BM * 64;
        #pragma unroll
        for (int m = 0; m < MH; ++m) {
            const int row = wr * WM + (mh * MH + m) * 16 + l15;
            #pragma unroll
            for (int kk = 0; kk < 2; ++kk)
                fa[m][kk] = *(const bf16x8*)(base + row * 64 + (((kk * 4 + q4) ^ l7) << 3));
        }
    };
    auto RD_FB = [&](int p, int nh) {
        const short* base = Bs + (size_t)p * BN * 64;
        #pragma unroll
        for (int j = 0; j < NH; ++j) {
            const int row = wc * WN + (nh * NH + j) * 16 + l15;
            #pragma unroll
            for (int kk = 0; kk < 2; ++kk)
                fb[nh * NH + j][kk] = *(const bf16x8*)(base + row * 64 + (((kk * 4 + q4) ^ l7) << 3));
        }
    };

#define VMGATE do {                                                            \
        if constexpr (VMN == 8) asm volatile("s_waitcnt vmcnt(8)" ::: "memory"); \
        else                    asm volatile("s_waitcnt vmcnt(6)" ::: "memory"); \
        __builtin_amdgcn_sched_barrier(0); } while (0)

#define MMAQ(mh, nh)                                                           \
    do {                                                                       \
        _Pragma("unroll")                                                      \
        for (int m_ = 0; m_ < MH; ++m_)                                        \
            _Pragma("unroll")                                                  \
            for (int j_ = 0; j_ < NH; ++j_)                                    \
                _Pragma("unroll")                                              \
                for (int kk_ = 0; kk_ < 2; ++kk_)                              \
                    acc[(mh) * MH + m_][(nh) * NH + j_] =                      \
                        __builtin_amdgcn_mfma_f32_16x16x32_bf16(               \
                            fa[m_][kk_], fb[(nh) * NH + j_][kk_],              \
                            acc[(mh) * MH + m_][(nh) * NH + j_], 0, 0, 0);     \
    } while (0)

    // ---- prologue: tile0 fully; tile1 B fully + A first chunks ----
    #pragma unroll
    for (int ch = 0; ch < CHA; ++ch) STG_A(0, ch);
    #pragma unroll
    for (int ch = 0; ch < CHB; ++ch) STG_B(0, ch);
    #pragma unroll
    for (int ch = 0; ch < CHB; ++ch) STG_B(1, ch);
    #pragma unroll
    for (int ch = 0; ch < (CHA == 4 ? 2 : CHA); ++ch) STG_A(1, ch);
    SB0;

    for (int T = 0; T < NT; ++T) {
        const int p = T & 1;
        // ---- P1: MMA(0,0); finish staging A(T+1) ----
        if constexpr (CHA == 4) {
            if (T + 1 < NT) { STG_A(T + 1, 2); STG_A(T + 1, 3); }
        }
        VMGATE;                       // tile T fully landed; T+1 still in flight
        RD_FA(p, 0); RD_FB(p, 0);
        __builtin_amdgcn_s_barrier(); SB0;
        LGKM0;
        __builtin_amdgcn_s_setprio(1); MMAQ(0, 0); __builtin_amdgcn_s_setprio(0);
        __builtin_amdgcn_s_barrier(); SB0;
        // ---- P2: MMA(0,1) ----
        RD_FB(p, 1);
        __builtin_amdgcn_s_barrier(); SB0;
        LGKM0;
        __builtin_amdgcn_s_setprio(1); MMAQ(0, 1); __builtin_amdgcn_s_setprio(0);
        __builtin_amdgcn_s_barrier(); SB0;
        // ---- P3: MMA(1,1); stage B(T+2) (B-region reads done at P2) ----
        RD_FA(p, 1);
        if (T + 2 < NT) { STG_B(T + 2, 0); STG_B(T + 2, 1); }
        __builtin_amdgcn_s_barrier(); SB0;
        LGKM0;
        __builtin_amdgcn_s_setprio(1); MMAQ(1, 1); __builtin_amdgcn_s_setprio(0);
        __builtin_amdgcn_s_barrier(); SB0;
        // ---- P4: MMA(1,0); stage B(T+2) rest + A(T+2) (A reads done at P3) ----
        if (T + 2 < NT) {
            STG_B(T + 2, 2); STG_B(T + 2, 3);
            STG_A(T + 2, 0); STG_A(T + 2, 1);
        }
        __builtin_amdgcn_s_barrier(); SB0;
        __builtin_amdgcn_s_setprio(1); MMAQ(1, 0); __builtin_amdgcn_s_setprio(0);
        __builtin_amdgcn_s_barrier(); SB0;
    }
#undef MMAQ
#undef VMGATE

    // ---- epilogue ----
    const int r_base = m0 + wr * WM + ((lane >> 4) << 2);
    const int c_base = n0 + wc * WN + (lane & 15);

    if constexpr (EP == 4) {
        // QKV pack. col: [0,1024)=q, [1024,2048)=k, [2048,3072)=v
        unsigned short* qP = (unsigned short*)outp;
        unsigned short* kP = qP + (size_t)NTOK * 1024;
        unsigned short* vP = qP + (size_t)2 * NTOK * 1024;
        const int b  = m0 >> 11;
        const int sb = (m0 & 2047) + wr * WM + ((lane >> 4) << 2);
        #pragma unroll
        for (int ni = 0; ni < NR; ++ni) {
            const int col = c_base + ni * 16;
            const int which = col >> 10;
            const int h = (col >> 6) & 15;
            const int d = col & 63;
            const float bv = bias[col];
            const size_t bh = (size_t)(b * NHEAD + h);
            if (which < 2) {
                unsigned short* dst = (which ? kP : qP) + bh * SEQ * 64 + d;
                #pragma unroll
                for (int mi = 0; mi < MR; ++mi)
                    #pragma unroll
                    for (int i = 0; i < 4; ++i)
                        dst[(size_t)(sb + mi * 16 + i) * 64] = f2bf(acc[mi][ni][i] + bv);
            } else {
                unsigned short* dst = vP + bh * SEQ * 64;
                #pragma unroll
                for (int mi = 0; mi < MR; ++mi) {
                    const int s0 = sb + mi * 16;
                    ushort4v o;
                    #pragma unroll
                    for (int i = 0; i < 4; ++i) o[i] = f2bf(acc[mi][ni][i] + bv);
                    *(ushort4v*)(dst + (s0 >> 5) * 2048 + d * 32 + (s0 & 31)) = o;
                }
            }
        }
        return;
    }

    #pragma unroll
    for (int ni = 0; ni < NR; ++ni) {
        const int col = c_base + ni * 16;
        const float bv = bias[col];
        #pragma unroll
        for (int mi = 0; mi < MR; ++mi) {
            #pragma unroll
            for (int i = 0; i < 4; ++i) {
                const int row = r_base + mi * 16 + i;
                const size_t idx = (size_t)row * N + col;
                float v = acc[mi][ni][i] + bv;
                if (EP == 1 || EP == 3) v += res[idx];
                if (EP == 2) v = 0.5f * v * (1.0f + erff(v * 0.70710678118f));
                if (EP == 0 || EP == 2) ((unsigned short*)outp)[idx] = f2bf(v);
                else                    ((float*)outp)[idx] = v;
            }
        }
    }
}

// ---------------- flash attention, swapped-QK^T 32x32, LDS-staged K/V ----------------
// qP/kP: [bh][s][64]; vP: [bh][kvblk][64 d][32 s]; o: [NTOK][1024]
__global__ __launch_bounds__(256, 4) void attn_kernel(
        const unsigned short* __restrict__ qP, const unsigned short* __restrict__ kP,
        const unsigned short* __restrict__ vP, unsigned short* __restrict__ o) {
    const int lane = threadIdx.x & 63;
    const int wid  = threadIdx.x >> 6;
    const int l31  = lane & 31;
    const int hi   = lane >> 5;
    const int bh = blockIdx.y;
    const int b = bh >> 4, h = bh & 15;
    const int q0 = blockIdx.x * 128 + wid * 32;   // this wave's 32 q rows

    __shared__ short Ks[2][2048];   // [32 row][8 chunk16] src-swizzled: chunk_src = c ^ (row&7)
    __shared__ short Vs[2][2048];   // [64 d][4 chunk16]  src-swizzled: chunk_src = c ^ ((d>>1)&3)
    __shared__ float lsum[4][32];

    // Q fragments (B-operand, col = q = l31, k = d-slice)
    bf16x8 qf[4];
    {
        const unsigned short* qp = qP + ((size_t)bh * SEQ + q0 + l31) * 64 + hi * 8;
        #pragma unroll
        for (int s = 0; s < 4; ++s) qf[s] = *(const bf16x8*)(qp + 16 * s);
    }

    // staging source offsets (elements), pre-swizzled so LDS dest stays linear
    const int krow  = wid * 8 + (lane >> 3);
    const int k_src = krow * 64 + (((lane & 7) ^ (lane >> 3)) << 3);
    const int vrow  = wid * 16 + (lane >> 2);
    const int v_src = vrow * 32 + (((lane & 3) ^ ((vrow >> 1) & 3)) << 3);
    const unsigned short* kb = kP + (size_t)bh * SEQ * 64 + k_src;
    const unsigned short* vb = vP + (size_t)bh * SEQ * 64 + v_src;
    short* ksd = &Ks[0][0] + wid * 512;   // wave-uniform LDS dest base
    short* vsd = &Vs[0][0] + wid * 512;

    auto STAGE = [&](int buf, int kv0) {
        gload_lds16(kb + (size_t)kv0 * 64, ksd + buf * 2048);
        gload_lds16(vb + (size_t)(kv0 >> 5) * 2048, vsd + buf * 2048);
    };

    STAGE(0, 0);
    asm volatile("s_waitcnt vmcnt(0)" ::: "memory");
    __builtin_amdgcn_s_barrier();

    f32x16 oacc0 = {}, oacc1 = {};
    float m_r = -1e30f, l_r = 0.0f;
    const float CE = 0.18033688011f;   // (1/8) * log2(e)

    for (int kv0 = 0; kv0 < SEQ; kv0 += 32) {
        const int cur = (kv0 >> 5) & 1;
        if (kv0 + 32 < SEQ) STAGE(cur ^ 1, kv0 + 32);

        const short* kc = &Ks[cur][0];
        const short* vc = &Vs[cur][0];
        // fragments from LDS (swizzled read)
        bf16x8 kf[4], vf[2][2];
        #pragma unroll
        for (int s = 0; s < 4; ++s)
            kf[s] = *(const bf16x8*)(kc + l31 * 64 + (((2 * s + hi) ^ (l31 & 7)) << 3));
        #pragma unroll
        for (int s = 0; s < 2; ++s)
            #pragma unroll
            for (int n = 0; n < 2; ++n) {
                const int d = l31 + 32 * n;
                vf[s][n] = *(const bf16x8*)(vc + d * 32 + (((2 * s + hi) ^ ((d >> 1) & 3)) << 3));
            }

        // QK^T: S^T[kv][q] = K * Q^T
        f32x16 S = {};
        #pragma unroll
        for (int s = 0; s < 4; ++s)
            S = __builtin_amdgcn_mfma_f32_32x32x16_bf16(kf[s], qf[s], S, 0, 0, 0);

        // online softmax: lane holds 16 kv-rows for one q (col = l31); tree reductions
        float t8[8];
        #pragma unroll
        for (int j = 0; j < 8; ++j) t8[j] = fmaxf(S[j], S[j + 8]);
        float tm = fmaxf(fmaxf(fmaxf(t8[0], t8[4]), fmaxf(t8[1], t8[5])),
                         fmaxf(fmaxf(t8[2], t8[6]), fmaxf(t8[3], t8[7])));
        tm = fmaxf(tm, __shfl_xor(tm, 32, 64));
        if (!__all(tm - m_r <= 44.0f)) {        // defer-max (T13): exp2 arg stays < 8
            const float mn = fmaxf(m_r, tm);
            const float es = exp2f((m_r - mn) * CE);
            l_r *= es;
            #pragma unroll
            for (int r = 0; r < 16; ++r) { oacc0[r] *= es; oacc1[r] *= es; }
            m_r = mn;
        }
        float p[16];
        #pragma unroll
        for (int r = 0; r < 16; ++r) p[r] = exp2f((S[r] - m_r) * CE);
        float a8[8];
        #pragma unroll
        for (int j = 0; j < 8; ++j) a8[j] = p[j] + p[j + 8];
        float rs = ((a8[0] + a8[4]) + (a8[1] + a8[5])) + ((a8[2] + a8[6]) + (a8[3] + a8[7]));
        rs += __shfl_xor(rs, 32, 64);
        l_r += rs;

        // P -> bf16 A-fragments via cvt_pk + permlane32_swap (T12)
        unsigned pk[8];
        #pragma unroll
        for (int i = 0; i < 8; ++i) {
            unsigned rr;
            asm("v_cvt_pk_bf16_f32 %0, %1, %2" : "=v"(rr) : "v"(p[2 * i]), "v"(p[2 * i + 1]));
            pk[i] = rr;
        }
        asm volatile("v_permlane32_swap_b32 %0, %1" : "+v"(pk[0]), "+v"(pk[2]));
        asm volatile("v_permlane32_swap_b32 %0, %1" : "+v"(pk[1]), "+v"(pk[3]));
        asm volatile("v_permlane32_swap_b32 %0, %1" : "+v"(pk[4]), "+v"(pk[6]));
        asm volatile("v_permlane32_swap_b32 %0, %1" : "+v"(pk[5]), "+v"(pk[7]));
        const bf16x8 A0 = __builtin_bit_cast(bf16x8, (u32x4){pk[0], pk[1], pk[2], pk[3]});
        const bf16x8 A1 = __builtin_bit_cast(bf16x8, (u32x4){pk[4], pk[5], pk[6], pk[7]});

        oacc0 = __builtin_amdgcn_mfma_f32_32x32x16_bf16(A0, vf[0][0], oacc0, 0, 0, 0);
        oacc1 = __builtin_amdgcn_mfma_f32_32x32x16_bf16(A0, vf[0][1], oacc1, 0, 0, 0);
        oacc0 = __builtin_amdgcn_mfma_f32_32x32x16_bf16(A1, vf[1][0], oacc0, 0, 0, 0);
        oacc1 = __builtin_amdgcn_mfma_f32_32x32x16_bf16(A1, vf[1][1], oacc1, 0, 0, 0);

        asm volatile("s_waitcnt vmcnt(0)" ::: "memory");
        __builtin_amdgcn_s_barrier();
    }

    // redistribute 1/l across lanes (O rows != S^T cols) via tiny per-wave LDS
    if (lane < 32) lsum[wid][l31] = 1.0f / l_r;
    float inv[16];
    #pragma unroll
    for (int r = 0; r < 16; ++r)
        inv[r] = lsum[wid][(r & 3) + 8 * (r >> 2) + 4 * hi];

    unsigned short* op = o + (size_t)(b * SEQ + q0) * DM + h * 64 + l31;
    #pragma unroll
    for (int r = 0; r < 16; ++r) {
        const int q = (r & 3) + 8 * (r >> 2) + 4 * hi;
        op[(size_t)q * DM]      = f2bf(oacc0[r] * inv[r]);
        op[(size_t)q * DM + 32] = f2bf(oacc1[r] * inv[r]);
    }
}

extern "C" void kernel_launch(void* const* d_in, const int* in_sizes, int n_in,
                              void* d_out, int out_size, void* d_ws, size_t ws_size,
                              hipStream_t stream) {
    const float* x    = (const float*)d_in[0];
    const float* Wq   = (const float*)d_in[1];
    const float* bq   = (const float*)d_in[2];
    const float* Wk   = (const float*)d_in[3];
    const float* bk   = (const float*)d_in[4];
    const float* Wv   = (const float*)d_in[5];
    const float* bv   = (const float*)d_in[6];
    const float* Wo   = (const float*)d_in[7];
    const float* bo   = (const float*)d_in[8];
    const float* ln1g = (const float*)d_in[9];
    const float* ln1b = (const float*)d_in[10];
    const float* ln2g = (const float*)d_in[11];
    const float* ln2b = (const float*)d_in[12];
    const float* W1   = (const float*)d_in[13];
    const float* b1   = (const float*)d_in[14];
    const float* W2   = (const float*)d_in[15];
    const float* b2   = (const float*)d_in[16];

    char* ws = (char*)d_ws;
    size_t off = 0;
    auto alloc = [&](size_t bytes) {
        char* p = ws + off;
        off = (off + bytes + 255) & ~(size_t)255;
        return p;
    };
    unsigned short* wqkvT = (unsigned short*)alloc((size_t)3072 * 1024 * 2);
    unsigned short* woT   = (unsigned short*)alloc((size_t)1024 * 1024 * 2);
    unsigned short* w1T   = (unsigned short*)alloc((size_t)4096 * 1024 * 2);
    unsigned short* w2T   = (unsigned short*)alloc((size_t)1024 * 4096 * 2);
    float*          bqkv  = (float*)alloc((size_t)3072 * 4);
    unsigned short* hbuf  = (unsigned short*)alloc((size_t)NTOK * DM * 2);
    unsigned short* pack  = (unsigned short*)alloc((size_t)NTOK * 3072 * 2);  // qP|kP|vP
    unsigned short* obuf  = (unsigned short*)alloc((size_t)NTOK * DM * 2);
    float*          x2    = (float*)alloc((size_t)NTOK * DM * 4);
    unsigned short* h2    = (unsigned short*)alloc((size_t)NTOK * DM * 2);
    unsigned short* gbuf  = (unsigned short*)alloc((size_t)NTOK * DFF * 2);

    const unsigned short* qP = pack;
    const unsigned short* kP = pack + (size_t)NTOK * 1024;
    const unsigned short* vP = pack + (size_t)2 * NTOK * 1024;

    // 1) weight transposes (fp32 -> bf16, [N][K])
    transpose_cvt<<<dim3(32, 32), 256, 0, stream>>>(Wq, wqkvT,                 1024, 1024);
    transpose_cvt<<<dim3(32, 32), 256, 0, stream>>>(Wk, wqkvT + 1024 * 1024,   1024, 1024);
    transpose_cvt<<<dim3(32, 32), 256, 0, stream>>>(Wv, wqkvT + 2 * 1024 * 1024, 1024, 1024);
    transpose_cvt<<<dim3(32, 32), 256, 0, stream>>>(Wo, woT,                   1024, 1024);
    transpose_cvt<<<dim3(128, 32), 256, 0, stream>>>(W1, w1T, 1024, 4096);
    transpose_cvt<<<dim3(32, 128), 256, 0, stream>>>(W2, w2T, 4096, 1024);
    concat_bias<<<12, 256, 0, stream>>>(bq, bk, bv, bqkv);

    // 2) LN1
    ln_kernel<<<NTOK, 256, 0, stream>>>(x, ln1g, ln1b, hbuf);

    // 3) QKV projection, packed epilogue: [8192,3072] -> qP/kP/vP  (768 blocks)
    gemmp<128, 256, 4><<<dim3(3072 / 256, NTOK / 128), 512, 0, stream>>>(
        hbuf, wqkvT, bqkv, nullptr, pack, NTOK, 3072, 1024);

    // 4) attention
    attn_kernel<<<dim3(SEQ / 128, NBATCH * NHEAD), 256, 0, stream>>>(qP, kP, vP, obuf);

    // 5) Wo projection + residual -> x2 (f32)  (256 blocks)
    gemmp<128, 256, 1><<<dim3(1024 / 256, NTOK / 128), 512, 0, stream>>>(
        obuf, woT, bo, x, x2, NTOK, 1024, 1024);

    // 6) LN2
    ln_kernel<<<NTOK, 256, 0, stream>>>(x2, ln2g, ln2b, h2);

    // 7) W1 + exact GELU  (512 blocks, 256x256)
    gemmp<256, 256, 2><<<dim3(4096 / 256, NTOK / 256), 512, 0, stream>>>(
        h2, w1T, b1, nullptr, gbuf, NTOK, 4096, 1024);

    // 8) W2 + residual -> out (f32)  (256 blocks, K=4096)
    gemmp<128, 256, 3><<<dim3(1024 / 256, NTOK / 128), 512, 0, stream>>>(
        gbuf, w2T, b2, x2, d_out, NTOK, 1024, 4096);

    (void)in_sizes; (void)n_in; (void)out_size; (void)ws_size;
}